// Round 11
// baseline (181.529 us; speedup 1.0000x reference)
//
#include <hip/hip_runtime.h>

#define FD 128
#define BN_EPS 1e-5f
#define BSH 8          // 256 dst nodes per bucket  (requires N <= 65536)
#define CAP 6144       // slots per bucket (mean 4082 for E=800k -> +32 sigma)
#define BE 8192        // edges per partition block
#define NGB 2048       // gather grid blocks (8 blocks/CU)
#define NRB 64         // stage-A reduction blocks

typedef short s8v __attribute__((ext_vector_type(8)));    // 8 bf16 bit-patterns
typedef float f4v __attribute__((ext_vector_type(4)));

__device__ __forceinline__ unsigned short f2bf(float f) {
    unsigned u = __float_as_uint(f);
    u += 0x7fff + ((u >> 16) & 1);           // RNE
    return (unsigned short)(u >> 16);
}
__device__ __forceinline__ unsigned pack2(float a, float b) {
    return (unsigned)f2bf(a) | ((unsigned)f2bf(b) << 16);
}
__device__ __forceinline__ float bf_lo(unsigned int u) {
    return __uint_as_float(u << 16);
}
__device__ __forceinline__ float bf_hi(unsigned int u) {
    return __uint_as_float(u & 0xffff0000u);
}
__device__ __forceinline__ float bfu(unsigned short s) {
    return __uint_as_float(((unsigned)s) << 16);
}

__device__ __forceinline__ int edge_get(const void* ei, int is64, size_t idx) {
    return is64 ? (int)((const long long*)ei)[idx] : ((const int*)ei)[idx];
}

// ---------------------------------------------------------------------------
// W prep (both layers) + zero gcur/done counters.
// ---------------------------------------------------------------------------
__global__ __launch_bounds__(256) void wprep_kernel(const float* __restrict__ W1,
                                                    const float* __restrict__ W2,
                                                    unsigned short* __restrict__ Wf1,
                                                    unsigned short* __restrict__ Wf2,
                                                    int* __restrict__ gcur) {
    int blk = blockIdx.x;
    if (blk == 0 && threadIdx.x < 258) gcur[threadIdx.x] = 0;   // gcur[256] + done[2]
    const float* W = (blk < 64) ? W1 : W2;
    unsigned short* Wf = (blk < 64) ? Wf1 : Wf2;
    int idx = (blk & 63) * 256 + threadIdx.x;   // 16384 total
    int j = idx & 7, lane = (idx >> 3) & 63, ct = (idx >> 9) & 7, kt = idx >> 12;
    int k = kt * 32 + (lane >> 4) * 8 + j;
    int c = ct * 16 + (lane & 15);
    Wf[idx] = f2bf(W[k * FD + c]);
}

// ---------------------------------------------------------------------------
// Phase 1: partition edges into 256-node dst-range buckets.
// Self-detects int32 vs int64 edge layout (deterministic 4KB prefix scan).
// Packed entry: src | (dst&255)<<24   (requires src < 2^24)
// ---------------------------------------------------------------------------
__global__ __launch_bounds__(256) void partition_kernel(const void* ei,
                                                        int* __restrict__ gcur,
                                                        unsigned* __restrict__ slab, int E) {
    __shared__ int any;
    __shared__ int hist[256];
    __shared__ int base[256];
    __shared__ int cur[256];
    int t = threadIdx.x;
    if (t == 0) any = 0;
    hist[t] = 0;
    __syncthreads();
    {   // format probe: odd int32 words all zero => int64
        const int* e32 = (const int*)ei;
        int limit = 2 * E < 4096 ? 2 * E : 4096;
        int found = 0;
        for (int i = t * 2 + 1; i < limit; i += 512)
            if (e32[i] != 0) { found = 1; break; }
        if (found) atomicOr(&any, 1);
    }
    __syncthreads();
    int is64 = any ? 0 : 1;
    int e0 = blockIdx.x * BE;
    int cnt = E - e0; if (cnt > BE) cnt = BE;
    for (int i = t; i < cnt; i += 256) {
        int d = edge_get(ei, is64, (size_t)E + e0 + i);
        atomicAdd(&hist[d >> BSH], 1);
    }
    __syncthreads();
    base[t] = hist[t] ? atomicAdd(&gcur[t], hist[t]) : 0;
    cur[t] = 0;
    __syncthreads();
    for (int i = t; i < cnt; i += 256) {
        int s = edge_get(ei, is64, e0 + i);
        int d = edge_get(ei, is64, (size_t)E + e0 + i);
        int b = d >> BSH;
        int r = atomicAdd(&cur[b], 1);
        int pos = base[b] + r;
        if (pos < CAP)
            slab[(size_t)b * CAP + pos] = (unsigned)s | ((unsigned)(d & 255) << 24);
    }
}

// ---------------------------------------------------------------------------
// Phase 2: one block per bucket -> dst-sorted colslab + nodemeta{start,cnt,dinv}.
// ---------------------------------------------------------------------------
__global__ __launch_bounds__(256) void bucket_csr_kernel(const unsigned* __restrict__ slab,
                                                         const int* __restrict__ gcur,
                                                         int* __restrict__ colslab,
                                                         uint4* __restrict__ nodemeta,
                                                         float* __restrict__ dinv, int n) {
    __shared__ int hist[256];
    __shared__ int loc[256];
    __shared__ int cur[256];
    __shared__ int tmp[256];
    int b = blockIdx.x, t = threadIdx.x;
    hist[t] = 0;
    __syncthreads();
    int cnt = gcur[b]; if (cnt > CAP) cnt = CAP;
    const unsigned* sl = slab + (size_t)b * CAP;
    for (int i = t; i < cnt; i += 256)
        atomicAdd(&hist[sl[i] >> 24], 1);
    __syncthreads();
    int v = hist[t];
    tmp[t] = v;
    __syncthreads();
    for (int off = 1; off < 256; off <<= 1) {
        int x = (t >= off) ? tmp[t - off] : 0;
        __syncthreads();
        tmp[t] += x;
        __syncthreads();
    }
    int start_loc = tmp[t] - v;              // exclusive prefix
    loc[t] = start_loc;
    cur[t] = 0;
    int node = (b << BSH) + t;
    if (node < n) {
        float dv = rsqrtf(1.0f + (float)v);
        dinv[node] = dv;
        nodemeta[node] = make_uint4((unsigned)(b * CAP + start_loc), (unsigned)v,
                                    __float_as_uint(dv), 0u);
    }
    __syncthreads();
    for (int i = t; i < cnt; i += 256) {
        unsigned e = sl[i];
        int dl = e >> 24;
        int r = atomicAdd(&cur[dl], 1);
        colslab[(size_t)b * CAP + loc[dl] + r] = (int)(e & 0xFFFFFF);
    }
}

// ---------------------------------------------------------------------------
// C[n,128] = (f(A[n,128]) @ W) * dinv[row], stored bf16.
// MODE 0: A = f32, f = bf16-cast.
// MODE 1: A = bf16 (packed), f = PReLU(A*sc + sh)  (fused BN+PReLU of layer 1).
// ---------------------------------------------------------------------------
template<int MODE>
__global__ __launch_bounds__(256) void gemm_mfma_kernel(const void* __restrict__ Ain,
                                                        const unsigned short* __restrict__ Wfrag,
                                                        const float* __restrict__ dinv,
                                                        const float4* __restrict__ scsh,
                                                        const float* __restrict__ aP,
                                                        unsigned short* __restrict__ C,
                                                        int n) {
    int wave = threadIdx.x >> 6, lane = threadIdx.x & 63;
    int rbase = blockIdx.x * 64 + wave * 16;
    int lrow = rbase + (lane & 15);
    int kg = lane >> 4;
    bool rok = lrow < n;
    float alpha = MODE ? aP[0] : 0.f;

    f4v acc[8];
#pragma unroll
    for (int i = 0; i < 8; ++i) acc[i] = (f4v){0.f, 0.f, 0.f, 0.f};

    const s8v* wf = (const s8v*)Wfrag;

#pragma unroll
    for (int kt = 0; kt < 4; ++kt) {
        s8v afr = (s8v){0, 0, 0, 0, 0, 0, 0, 0};
        if (rok) {
            float4 u0, u1;
            if (MODE) {
                const unsigned short* A = (const unsigned short*)Ain;
                s8v raw = *(const s8v*)(A + (size_t)lrow * FD + kt * 32 + kg * 8);
                u0.x = bfu((unsigned short)raw[0]); u0.y = bfu((unsigned short)raw[1]);
                u0.z = bfu((unsigned short)raw[2]); u0.w = bfu((unsigned short)raw[3]);
                u1.x = bfu((unsigned short)raw[4]); u1.y = bfu((unsigned short)raw[5]);
                u1.z = bfu((unsigned short)raw[6]); u1.w = bfu((unsigned short)raw[7]);
                int c4 = kt * 8 + kg * 2;            // float4-group index of col
                float4 sc0 = scsh[c4],      sh0 = scsh[32 + c4];
                float4 sc1 = scsh[c4 + 1],  sh1 = scsh[32 + c4 + 1];
                u0.x = u0.x * sc0.x + sh0.x; u0.y = u0.y * sc0.y + sh0.y;
                u0.z = u0.z * sc0.z + sh0.z; u0.w = u0.w * sc0.w + sh0.w;
                u1.x = u1.x * sc1.x + sh1.x; u1.y = u1.y * sc1.y + sh1.y;
                u1.z = u1.z * sc1.z + sh1.z; u1.w = u1.w * sc1.w + sh1.w;
                u0.x = u0.x >= 0.f ? u0.x : alpha * u0.x;
                u0.y = u0.y >= 0.f ? u0.y : alpha * u0.y;
                u0.z = u0.z >= 0.f ? u0.z : alpha * u0.z;
                u0.w = u0.w >= 0.f ? u0.w : alpha * u0.w;
                u1.x = u1.x >= 0.f ? u1.x : alpha * u1.x;
                u1.y = u1.y >= 0.f ? u1.y : alpha * u1.y;
                u1.z = u1.z >= 0.f ? u1.z : alpha * u1.z;
                u1.w = u1.w >= 0.f ? u1.w : alpha * u1.w;
            } else {
                const float* A = (const float*)Ain;
                const float* p = A + (size_t)lrow * FD + kt * 32 + kg * 8;
                u0 = *(const float4*)p;
                u1 = *(const float4*)(p + 4);
            }
            afr[0] = (short)f2bf(u0.x); afr[1] = (short)f2bf(u0.y);
            afr[2] = (short)f2bf(u0.z); afr[3] = (short)f2bf(u0.w);
            afr[4] = (short)f2bf(u1.x); afr[5] = (short)f2bf(u1.y);
            afr[6] = (short)f2bf(u1.z); afr[7] = (short)f2bf(u1.w);
        }
#pragma unroll
        for (int ct = 0; ct < 8; ++ct) {
            s8v bfr = wf[(kt * 8 + ct) * 64 + lane];
            acc[ct] = __builtin_amdgcn_mfma_f32_16x16x32_bf16(afr, bfr, acc[ct], 0, 0, 0);
        }
    }

    int col0 = lane & 15;
#pragma unroll
    for (int r = 0; r < 4; ++r) {
        int row = rbase + kg * 4 + r;
        if (row < n) {
            float dv = dinv[row];
            unsigned short* crow = C + (size_t)row * FD;
#pragma unroll
            for (int ct = 0; ct < 8; ++ct)
                crow[ct * 16 + col0] = f2bf(acc[ct][r] * dv);
        }
    }
}

// ---------------------------------------------------------------------------
// CSR gather + fused BN stats. One 32-lane half per node; within the half,
// lanes split as (g = parity group 0/1, c = uint4 column 0..15). Each lane
// loads 16B (8 bf16 cols c*8..c*8+7); group g walks neighbors j = g, g+2, ...
// 4 rows in flight per group (8 per half). Merge groups via shfl_xor(16).
// Stats on pre-round f32; agg stored packed bf16. Block 0 resets 'done'.
// ---------------------------------------------------------------------------
__global__ __launch_bounds__(256) void gather_stats_kernel(const uint4* __restrict__ hs4,
                                                           const uint4* __restrict__ nodemeta,
                                                           const int* __restrict__ col,
                                                           const float* __restrict__ b,
                                                           uint4* __restrict__ aggb4,
                                                           float* __restrict__ partialf,
                                                           int* __restrict__ done,
                                                           int n) {
    __shared__ float redS[1024];
    __shared__ float redQ[1024];
    int tid = threadIdx.x;
    if (blockIdx.x == 0 && tid == 0) done[0] = 0;    // reset ticket for this layer
    int half = tid >> 5;                  // 0..7
    int g = (tid >> 4) & 1;               // parity group
    int c = tid & 15;                     // uint4 column
    int hid = blockIdx.x * 8 + half;

    float bb[8];
    {
        const float4* b4 = (const float4*)b;
        float4 blo = b4[c * 2], bhi = b4[c * 2 + 1];
        bb[0] = blo.x; bb[1] = blo.y; bb[2] = blo.z; bb[3] = blo.w;
        bb[4] = bhi.x; bb[5] = bhi.y; bb[6] = bhi.z; bb[7] = bhi.w;
    }
    float ss[8], sq[8];
#pragma unroll
    for (int k = 0; k < 8; ++k) { ss[k] = 0.f; sq[k] = 0.f; }

    for (int wid = hid; wid < n; wid += NGB * 8) {
        uint4 m = nodemeta[wid];
        int i0 = (int)m.x, cnt = (int)m.y;
        float dv = __uint_as_float(m.z);
        float a[8];
#pragma unroll
        for (int k = 0; k < 8; ++k) a[k] = 0.f;
        if (g == 0) {                              // self term
            uint4 u = hs4[(size_t)wid * 16 + c];
            a[0] += bf_lo(u.x); a[1] += bf_hi(u.x); a[2] += bf_lo(u.y); a[3] += bf_hi(u.y);
            a[4] += bf_lo(u.z); a[5] += bf_hi(u.z); a[6] += bf_lo(u.w); a[7] += bf_hi(u.w);
        }
        int j = g;
        for (; j + 6 < cnt; j += 8) {
            int s0 = col[i0 + j],     s1 = col[i0 + j + 2];
            int s2 = col[i0 + j + 4], s3 = col[i0 + j + 6];
            uint4 u0 = hs4[(size_t)s0 * 16 + c];
            uint4 u1 = hs4[(size_t)s1 * 16 + c];
            uint4 u2 = hs4[(size_t)s2 * 16 + c];
            uint4 u3 = hs4[(size_t)s3 * 16 + c];
            a[0] += bf_lo(u0.x) + bf_lo(u1.x) + bf_lo(u2.x) + bf_lo(u3.x);
            a[1] += bf_hi(u0.x) + bf_hi(u1.x) + bf_hi(u2.x) + bf_hi(u3.x);
            a[2] += bf_lo(u0.y) + bf_lo(u1.y) + bf_lo(u2.y) + bf_lo(u3.y);
            a[3] += bf_hi(u0.y) + bf_hi(u1.y) + bf_hi(u2.y) + bf_hi(u3.y);
            a[4] += bf_lo(u0.z) + bf_lo(u1.z) + bf_lo(u2.z) + bf_lo(u3.z);
            a[5] += bf_hi(u0.z) + bf_hi(u1.z) + bf_hi(u2.z) + bf_hi(u3.z);
            a[6] += bf_lo(u0.w) + bf_lo(u1.w) + bf_lo(u2.w) + bf_lo(u3.w);
            a[7] += bf_hi(u0.w) + bf_hi(u1.w) + bf_hi(u2.w) + bf_hi(u3.w);
        }
        for (; j < cnt; j += 2) {
            int s = col[i0 + j];
            uint4 u = hs4[(size_t)s * 16 + c];
            a[0] += bf_lo(u.x); a[1] += bf_hi(u.x); a[2] += bf_lo(u.y); a[3] += bf_hi(u.y);
            a[4] += bf_lo(u.z); a[5] += bf_hi(u.z); a[6] += bf_lo(u.w); a[7] += bf_hi(u.w);
        }
#pragma unroll
        for (int k = 0; k < 8; ++k) a[k] += __shfl_xor(a[k], 16);
        if (g == 0) {
            float o[8];
#pragma unroll
            for (int k = 0; k < 8; ++k) o[k] = dv * a[k] + bb[k];
            uint4 w;
            w.x = pack2(o[0], o[1]); w.y = pack2(o[2], o[3]);
            w.z = pack2(o[4], o[5]); w.w = pack2(o[6], o[7]);
            aggb4[(size_t)wid * 16 + c] = w;
#pragma unroll
            for (int k = 0; k < 8; ++k) { ss[k] += o[k]; sq[k] += o[k] * o[k]; }
        }
    }
    if (g == 0) {
#pragma unroll
        for (int k = 0; k < 8; ++k) {
            redS[half * 128 + c * 8 + k] = ss[k];
            redQ[half * 128 + c * 8 + k] = sq[k];
        }
    }
    __syncthreads();
    if (tid < 128) {
        float s = 0.f, q = 0.f;
#pragma unroll
        for (int h = 0; h < 8; ++h) {
            s += redS[h * 128 + tid];
            q += redQ[h * 128 + tid];
        }
        partialf[(size_t)blockIdx.x * 256 + tid] = s;
        partialf[(size_t)blockIdx.x * 256 + 128 + tid] = q;
    }
}

// ---------------------------------------------------------------------------
// Stage A+B fused: each block reduces 32 partial rows -> partial2[b]; the
// last block (atomic ticket) reduces the 64 partial2 rows and emits scale/
// shift. Deterministic: all sums fixed-order; ticket only gates timing.
// ---------------------------------------------------------------------------
__global__ __launch_bounds__(256) void reduce_finalize_kernel(const float4* __restrict__ partial,
                                                              float4* __restrict__ partial2,
                                                              int* __restrict__ done,
                                                              const float* __restrict__ g,
                                                              const float* __restrict__ be,
                                                              float4* __restrict__ scsh,
                                                              float invn) {
    __shared__ float4 red[256];
    __shared__ int isLast;
    int t = threadIdx.x;
    int e = t & 63;
    int sr = t >> 6;                      // 0..3
    {
        int r0 = blockIdx.x * 32;
        float4 acc = {0.f, 0.f, 0.f, 0.f};
        for (int r = sr; r < 32; r += 4) {
            float4 v = partial[(size_t)(r0 + r) * 64 + e];
            acc.x += v.x; acc.y += v.y; acc.z += v.z; acc.w += v.w;
        }
        red[t] = acc;
        __syncthreads();
        if (sr < 2) {
            float4 o = red[t + 128];
            red[t].x += o.x; red[t].y += o.y; red[t].z += o.z; red[t].w += o.w;
        }
        __syncthreads();
        if (sr == 0) {
            float4 o = red[t + 64];
            float4 s = red[t];
            s.x += o.x; s.y += o.y; s.z += o.z; s.w += o.w;
            partial2[(size_t)blockIdx.x * 64 + e] = s;
        }
    }
    __syncthreads();
    __threadfence();
    if (t == 0) isLast = (atomicAdd(done, 1) == (int)gridDim.x - 1);
    __syncthreads();
    if (!isLast) return;
    __threadfence();
    // stage B
    float4 acc = {0.f, 0.f, 0.f, 0.f};
    for (int r = sr; r < NRB; r += 4) {
        float4 v = partial2[(size_t)r * 64 + e];
        acc.x += v.x; acc.y += v.y; acc.z += v.z; acc.w += v.w;
    }
    __syncthreads();
    red[t] = acc;
    __syncthreads();
    if (sr < 2) {
        float4 o = red[t + 128];
        red[t].x += o.x; red[t].y += o.y; red[t].z += o.z; red[t].w += o.w;
    }
    __syncthreads();
    if (sr == 0) {
        float4 o = red[t + 64];
        red[t].x += o.x; red[t].y += o.y; red[t].z += o.z; red[t].w += o.w;
    }
    __syncthreads();
    if (t < 32) {
        float4 s = red[t];
        float4 qq = red[32 + t];
        float4 gg = ((const float4*)g)[t];
        float4 bbe = ((const float4*)be)[t];
        float4 mu, var, sc, sh;
        mu.x = s.x * invn; mu.y = s.y * invn; mu.z = s.z * invn; mu.w = s.w * invn;
        var.x = qq.x * invn - mu.x * mu.x; var.y = qq.y * invn - mu.y * mu.y;
        var.z = qq.z * invn - mu.z * mu.z; var.w = qq.w * invn - mu.w * mu.w;
        sc.x = gg.x * rsqrtf(var.x + BN_EPS); sc.y = gg.y * rsqrtf(var.y + BN_EPS);
        sc.z = gg.z * rsqrtf(var.z + BN_EPS); sc.w = gg.w * rsqrtf(var.w + BN_EPS);
        sh.x = bbe.x - mu.x * sc.x; sh.y = bbe.y - mu.y * sc.y;
        sh.z = bbe.z - mu.z * sc.z; sh.w = bbe.w - mu.w * sc.w;
        scsh[t] = sc;
        scsh[32 + t] = sh;
    }
}

// ---------------------------------------------------------------------------
// Final BN + PReLU: bf16 agg -> f32 output.
// ---------------------------------------------------------------------------
__global__ __launch_bounds__(256) void bn_apply_kernel(const uint2* __restrict__ aggb,
                                                       const float4* __restrict__ scsh,
                                                       const float* __restrict__ aP,
                                                       float4* __restrict__ out, int n) {
    int t = blockIdx.x * 256 + threadIdx.x;
    if (t >= n * 32) return;
    int c4 = t & 31;
    float alpha = aP[0];
    uint2 u = aggb[t];
    float4 v;
    v.x = bf_lo(u.x); v.y = bf_hi(u.x); v.z = bf_lo(u.y); v.w = bf_hi(u.y);
    float4 sc = scsh[c4];
    float4 sh = scsh[32 + c4];
    float4 y;
    y.x = v.x * sc.x + sh.x; y.y = v.y * sc.y + sh.y;
    y.z = v.z * sc.z + sh.z; y.w = v.w * sc.w + sh.w;
    y.x = y.x >= 0.f ? y.x : alpha * y.x;
    y.y = y.y >= 0.f ? y.y : alpha * y.y;
    y.z = y.z >= 0.f ? y.z : alpha * y.z;
    y.w = y.w >= 0.f ? y.w : alpha * y.w;
    out[t] = y;
}

// ---------------------------------------------------------------------------

extern "C" void kernel_launch(void* const* d_in, const int* in_sizes, int n_in,
                              void* d_out, int out_size, void* d_ws, size_t ws_size,
                              hipStream_t stream) {
    const float* x  = (const float*)d_in[0];
    const void*  ei = d_in[1];
    const float* W1 = (const float*)d_in[2];
    const float* b1 = (const float*)d_in[3];
    const float* g1 = (const float*)d_in[4];
    const float* be1= (const float*)d_in[5];
    const float* a1 = (const float*)d_in[6];
    const float* W2 = (const float*)d_in[7];
    const float* b2 = (const float*)d_in[8];
    const float* g2 = (const float*)d_in[9];
    const float* be2= (const float*)d_in[10];
    const float* a2 = (const float*)d_in[11];

    int N = in_sizes[0] / FD;
    int E = in_sizes[1] / 2;
    float* out = (float*)d_out;

    int nbuck = (N + (1 << BSH) - 1) >> BSH;   // 196 for N=50000 (<=256 required)

    char* ws = (char*)d_ws;
    size_t off = 0;
    auto alloc = [&](size_t bytes) {
        void* p = ws + off;
        off += (bytes + 255) & ~(size_t)255;
        return p;
    };
    float* dinv    = (float*)alloc((size_t)N * 4);
    int*   gcur    = (int*)alloc(260 * 4);     // gcur[256] + done[2] (+pad)
    int*   done    = gcur + 256;
    uint4* nodemeta= (uint4*)alloc((size_t)N * 16);
    unsigned* slab = (unsigned*)alloc((size_t)nbuck * CAP * 4);
    int*   colslab = (int*)alloc((size_t)nbuck * CAP * 4);
    unsigned short* wf1 = (unsigned short*)alloc((size_t)FD * FD * 2);
    unsigned short* wf2 = (unsigned short*)alloc((size_t)FD * FD * 2);
    unsigned short* hs  = (unsigned short*)alloc((size_t)N * FD * 2);
    uint4* aggb    = (uint4*)alloc((size_t)N * FD * 2);
    float* partialf= (float*)alloc((size_t)NGB * 256 * 4);
    float4* partial2=(float4*)alloc((size_t)NRB * 64 * 16);
    float4* scsh   = (float4*)alloc(64 * 16);
    (void)ws_size; (void)n_in; (void)out_size;

    // wprep also zeroes gcur/done
    wprep_kernel<<<128, 256, 0, stream>>>(W1, W2, wf1, wf2, gcur);

    // CSR build (once; reused by both layers)
    partition_kernel<<<(E + BE - 1) / BE, 256, 0, stream>>>(ei, gcur, slab, E);
    bucket_csr_kernel<<<nbuck, 256, 0, stream>>>(slab, gcur, colslab, nodemeta, dinv, N);

    int gemm_blocks = (N + 63) / 64;
    int nt = N * 32;
    float invn = 1.0f / (float)N;

    // ---- layer 1 ----
    gemm_mfma_kernel<0><<<gemm_blocks, 256, 0, stream>>>(x, wf1, dinv, nullptr, nullptr,
                                                         hs, N);
    gather_stats_kernel<<<NGB, 256, 0, stream>>>((const uint4*)hs, nodemeta, colslab,
                                                 b1, aggb, partialf, done, N);
    reduce_finalize_kernel<<<NRB, 256, 0, stream>>>((const float4*)partialf, partial2,
                                                    done, g1, be1, scsh, invn);

    // ---- layer 2 (BN1+PReLU1 fused into A-load, bf16 A) ----
    gemm_mfma_kernel<1><<<gemm_blocks, 256, 0, stream>>>(aggb, wf2, dinv,
                                                         scsh, a1, hs, N);
    gather_stats_kernel<<<NGB, 256, 0, stream>>>((const uint4*)hs, nodemeta, colslab,
                                                 b2, aggb, partialf, done, N);
    reduce_finalize_kernel<<<NRB, 256, 0, stream>>>((const float4*)partialf, partial2,
                                                    done, g2, be2, scsh, invn);
    bn_apply_kernel<<<(nt + 255) / 256, 256, 0, stream>>>((const uint2*)aggb, scsh, a2,
                                                          (float4*)out, N);
}

// Round 12
// 162.318 us; speedup vs baseline: 1.1184x; 1.1184x over previous
//
#include <hip/hip_runtime.h>

#define FD 128
#define BN_EPS 1e-5f
#define BSH 8          // 256 dst nodes per bucket  (requires N <= 65536)
#define CAP 6144       // slots per bucket (mean 4082 for E=800k -> +32 sigma)
#define BE 8192        // edges per partition block
#define NGB 2048       // gather grid blocks (8 blocks/CU)
#define NRB 64         // stage-A reduction blocks

typedef short s8v __attribute__((ext_vector_type(8)));    // 8 bf16 bit-patterns
typedef float f4v __attribute__((ext_vector_type(4)));

__device__ __forceinline__ unsigned short f2bf(float f) {
    unsigned u = __float_as_uint(f);
    u += 0x7fff + ((u >> 16) & 1);           // RNE
    return (unsigned short)(u >> 16);
}
__device__ __forceinline__ unsigned pack2(float a, float b) {
    return (unsigned)f2bf(a) | ((unsigned)f2bf(b) << 16);
}
__device__ __forceinline__ float bf_lo(unsigned int u) {
    return __uint_as_float(u << 16);
}
__device__ __forceinline__ float bf_hi(unsigned int u) {
    return __uint_as_float(u & 0xffff0000u);
}
__device__ __forceinline__ float bfu(unsigned short s) {
    return __uint_as_float(((unsigned)s) << 16);
}

__device__ __forceinline__ int edge_get(const void* ei, int is64, size_t idx) {
    return is64 ? (int)((const long long*)ei)[idx] : ((const int*)ei)[idx];
}

// ---------------------------------------------------------------------------
// W prep (both layers); block 0 also zeroes gcur[256]. Runs before partition.
// ---------------------------------------------------------------------------
__global__ __launch_bounds__(256) void wprep_kernel(const float* __restrict__ W1,
                                                    const float* __restrict__ W2,
                                                    unsigned short* __restrict__ Wf1,
                                                    unsigned short* __restrict__ Wf2,
                                                    int* __restrict__ gcur) {
    int blk = blockIdx.x;
    if (blk == 0) gcur[threadIdx.x] = 0;
    const float* W = (blk < 64) ? W1 : W2;
    unsigned short* Wf = (blk < 64) ? Wf1 : Wf2;
    int idx = (blk & 63) * 256 + threadIdx.x;   // 16384 total
    int j = idx & 7, lane = (idx >> 3) & 63, ct = (idx >> 9) & 7, kt = idx >> 12;
    int k = kt * 32 + (lane >> 4) * 8 + j;
    int c = ct * 16 + (lane & 15);
    Wf[idx] = f2bf(W[k * FD + c]);
}

// ---------------------------------------------------------------------------
// Phase 1: partition edges into 256-node dst-range buckets.
// Self-detects int32 vs int64 edge layout (deterministic 4KB prefix scan).
// Packed entry: src | (dst&255)<<24   (requires src < 2^24)
// ---------------------------------------------------------------------------
__global__ __launch_bounds__(256) void partition_kernel(const void* ei,
                                                        int* __restrict__ gcur,
                                                        unsigned* __restrict__ slab, int E) {
    __shared__ int any;
    __shared__ int hist[256];
    __shared__ int base[256];
    __shared__ int cur[256];
    int t = threadIdx.x;
    if (t == 0) any = 0;
    hist[t] = 0;
    __syncthreads();
    {   // format probe: odd int32 words all zero => int64
        const int* e32 = (const int*)ei;
        int limit = 2 * E < 4096 ? 2 * E : 4096;
        int found = 0;
        for (int i = t * 2 + 1; i < limit; i += 512)
            if (e32[i] != 0) { found = 1; break; }
        if (found) atomicOr(&any, 1);
    }
    __syncthreads();
    int is64 = any ? 0 : 1;
    int e0 = blockIdx.x * BE;
    int cnt = E - e0; if (cnt > BE) cnt = BE;
    for (int i = t; i < cnt; i += 256) {
        int d = edge_get(ei, is64, (size_t)E + e0 + i);
        atomicAdd(&hist[d >> BSH], 1);
    }
    __syncthreads();
    base[t] = hist[t] ? atomicAdd(&gcur[t], hist[t]) : 0;
    cur[t] = 0;
    __syncthreads();
    for (int i = t; i < cnt; i += 256) {
        int s = edge_get(ei, is64, e0 + i);
        int d = edge_get(ei, is64, (size_t)E + e0 + i);
        int b = d >> BSH;
        int r = atomicAdd(&cur[b], 1);
        int pos = base[b] + r;
        if (pos < CAP)
            slab[(size_t)b * CAP + pos] = (unsigned)s | ((unsigned)(d & 255) << 24);
    }
}

// ---------------------------------------------------------------------------
// Phase 2: one block per bucket -> dst-sorted colslab + nodemeta{start,cnt,dinv}.
// ---------------------------------------------------------------------------
__global__ __launch_bounds__(256) void bucket_csr_kernel(const unsigned* __restrict__ slab,
                                                         const int* __restrict__ gcur,
                                                         int* __restrict__ colslab,
                                                         uint4* __restrict__ nodemeta,
                                                         float* __restrict__ dinv, int n) {
    __shared__ int hist[256];
    __shared__ int loc[256];
    __shared__ int cur[256];
    __shared__ int tmp[256];
    int b = blockIdx.x, t = threadIdx.x;
    hist[t] = 0;
    __syncthreads();
    int cnt = gcur[b]; if (cnt > CAP) cnt = CAP;
    const unsigned* sl = slab + (size_t)b * CAP;
    for (int i = t; i < cnt; i += 256)
        atomicAdd(&hist[sl[i] >> 24], 1);
    __syncthreads();
    int v = hist[t];
    tmp[t] = v;
    __syncthreads();
    for (int off = 1; off < 256; off <<= 1) {
        int x = (t >= off) ? tmp[t - off] : 0;
        __syncthreads();
        tmp[t] += x;
        __syncthreads();
    }
    int start_loc = tmp[t] - v;              // exclusive prefix
    loc[t] = start_loc;
    cur[t] = 0;
    int node = (b << BSH) + t;
    if (node < n) {
        float dv = rsqrtf(1.0f + (float)v);
        dinv[node] = dv;
        nodemeta[node] = make_uint4((unsigned)(b * CAP + start_loc), (unsigned)v,
                                    __float_as_uint(dv), 0u);
    }
    __syncthreads();
    for (int i = t; i < cnt; i += 256) {
        unsigned e = sl[i];
        int dl = e >> 24;
        int r = atomicAdd(&cur[dl], 1);
        colslab[(size_t)b * CAP + loc[dl] + r] = (int)(e & 0xFFFFFF);
    }
}

// ---------------------------------------------------------------------------
// C[n,128] = (f(A[n,128]) @ W) * dinv[row], stored bf16.
// MODE 0: A = f32, f = bf16-cast.
// MODE 1: A = bf16 (packed), f = PReLU(A*sc + sh)  (fused BN+PReLU of layer 1).
// ---------------------------------------------------------------------------
template<int MODE>
__global__ __launch_bounds__(256) void gemm_mfma_kernel(const void* __restrict__ Ain,
                                                        const unsigned short* __restrict__ Wfrag,
                                                        const float* __restrict__ dinv,
                                                        const float4* __restrict__ scsh,
                                                        const float* __restrict__ aP,
                                                        unsigned short* __restrict__ C,
                                                        int n) {
    int wave = threadIdx.x >> 6, lane = threadIdx.x & 63;
    int rbase = blockIdx.x * 64 + wave * 16;
    int lrow = rbase + (lane & 15);
    int kg = lane >> 4;
    bool rok = lrow < n;
    float alpha = MODE ? aP[0] : 0.f;

    f4v acc[8];
#pragma unroll
    for (int i = 0; i < 8; ++i) acc[i] = (f4v){0.f, 0.f, 0.f, 0.f};

    const s8v* wf = (const s8v*)Wfrag;

#pragma unroll
    for (int kt = 0; kt < 4; ++kt) {
        s8v afr = (s8v){0, 0, 0, 0, 0, 0, 0, 0};
        if (rok) {
            float4 u0, u1;
            if (MODE) {
                const unsigned short* A = (const unsigned short*)Ain;
                s8v raw = *(const s8v*)(A + (size_t)lrow * FD + kt * 32 + kg * 8);
                u0.x = bfu((unsigned short)raw[0]); u0.y = bfu((unsigned short)raw[1]);
                u0.z = bfu((unsigned short)raw[2]); u0.w = bfu((unsigned short)raw[3]);
                u1.x = bfu((unsigned short)raw[4]); u1.y = bfu((unsigned short)raw[5]);
                u1.z = bfu((unsigned short)raw[6]); u1.w = bfu((unsigned short)raw[7]);
                int c4 = kt * 8 + kg * 2;            // float4-group index of col
                float4 sc0 = scsh[c4],      sh0 = scsh[32 + c4];
                float4 sc1 = scsh[c4 + 1],  sh1 = scsh[32 + c4 + 1];
                u0.x = u0.x * sc0.x + sh0.x; u0.y = u0.y * sc0.y + sh0.y;
                u0.z = u0.z * sc0.z + sh0.z; u0.w = u0.w * sc0.w + sh0.w;
                u1.x = u1.x * sc1.x + sh1.x; u1.y = u1.y * sc1.y + sh1.y;
                u1.z = u1.z * sc1.z + sh1.z; u1.w = u1.w * sc1.w + sh1.w;
                u0.x = u0.x >= 0.f ? u0.x : alpha * u0.x;
                u0.y = u0.y >= 0.f ? u0.y : alpha * u0.y;
                u0.z = u0.z >= 0.f ? u0.z : alpha * u0.z;
                u0.w = u0.w >= 0.f ? u0.w : alpha * u0.w;
                u1.x = u1.x >= 0.f ? u1.x : alpha * u1.x;
                u1.y = u1.y >= 0.f ? u1.y : alpha * u1.y;
                u1.z = u1.z >= 0.f ? u1.z : alpha * u1.z;
                u1.w = u1.w >= 0.f ? u1.w : alpha * u1.w;
            } else {
                const float* A = (const float*)Ain;
                const float* p = A + (size_t)lrow * FD + kt * 32 + kg * 8;
                u0 = *(const float4*)p;
                u1 = *(const float4*)(p + 4);
            }
            afr[0] = (short)f2bf(u0.x); afr[1] = (short)f2bf(u0.y);
            afr[2] = (short)f2bf(u0.z); afr[3] = (short)f2bf(u0.w);
            afr[4] = (short)f2bf(u1.x); afr[5] = (short)f2bf(u1.y);
            afr[6] = (short)f2bf(u1.z); afr[7] = (short)f2bf(u1.w);
        }
#pragma unroll
        for (int ct = 0; ct < 8; ++ct) {
            s8v bfr = wf[(kt * 8 + ct) * 64 + lane];
            acc[ct] = __builtin_amdgcn_mfma_f32_16x16x32_bf16(afr, bfr, acc[ct], 0, 0, 0);
        }
    }

    int col0 = lane & 15;
#pragma unroll
    for (int r = 0; r < 4; ++r) {
        int row = rbase + kg * 4 + r;
        if (row < n) {
            float dv = dinv[row];
            unsigned short* crow = C + (size_t)row * FD;
#pragma unroll
            for (int ct = 0; ct < 8; ++ct)
                crow[ct * 16 + col0] = f2bf(acc[ct][r] * dv);
        }
    }
}

// ---------------------------------------------------------------------------
// CSR gather + fused BN stats. One 32-lane HALF per node (grid-stride),
// uint2 = 4 bf16 per lane, 4 neighbor rows in flight. Stats accumulated on
// pre-round f32; agg stored as packed bf16. Per-block partials -> global.
// ---------------------------------------------------------------------------
__global__ __launch_bounds__(256) void gather_stats_kernel(const uint2* __restrict__ hs2,
                                                           const uint4* __restrict__ nodemeta,
                                                           const int* __restrict__ col,
                                                           const float* __restrict__ b,
                                                           uint2* __restrict__ aggb,
                                                           float4* __restrict__ partial,
                                                           int n) {
    __shared__ float4 redS[256];
    __shared__ float4 redQ[256];
    int tid = threadIdx.x;
    int hid = blockIdx.x * 8 + (tid >> 5);        // global half-wave id
    int q = tid & 31;                             // float4 column group
    float4 bb = ((const float4*)b)[q];

    float4 ssum = {0.f, 0.f, 0.f, 0.f};
    float4 ssq  = {0.f, 0.f, 0.f, 0.f};

    for (int wid = hid; wid < n; wid += NGB * 8) {
        uint4 m = nodemeta[wid];
        int i0 = (int)m.x, cnt = (int)m.y;
        float dv = __uint_as_float(m.z);
        uint2 u = hs2[(size_t)wid * 32 + q];      // self term
        float ax = bf_lo(u.x), ay = bf_hi(u.x), az = bf_lo(u.y), aw = bf_hi(u.y);
        int j = 0;
        for (; j + 4 <= cnt; j += 4) {
            int s0 = col[i0 + j], s1 = col[i0 + j + 1];
            int s2 = col[i0 + j + 2], s3 = col[i0 + j + 3];
            uint2 u0 = hs2[(size_t)s0 * 32 + q];
            uint2 u1 = hs2[(size_t)s1 * 32 + q];
            uint2 u2 = hs2[(size_t)s2 * 32 + q];
            uint2 u3 = hs2[(size_t)s3 * 32 + q];
            ax += bf_lo(u0.x) + bf_lo(u1.x) + bf_lo(u2.x) + bf_lo(u3.x);
            ay += bf_hi(u0.x) + bf_hi(u1.x) + bf_hi(u2.x) + bf_hi(u3.x);
            az += bf_lo(u0.y) + bf_lo(u1.y) + bf_lo(u2.y) + bf_lo(u3.y);
            aw += bf_hi(u0.y) + bf_hi(u1.y) + bf_hi(u2.y) + bf_hi(u3.y);
        }
        for (; j < cnt; ++j) {
            int s = col[i0 + j];
            uint2 uu = hs2[(size_t)s * 32 + q];
            ax += bf_lo(uu.x); ay += bf_hi(uu.x); az += bf_lo(uu.y); aw += bf_hi(uu.y);
        }
        float4 o;
        o.x = dv * ax + bb.x; o.y = dv * ay + bb.y;
        o.z = dv * az + bb.z; o.w = dv * aw + bb.w;
        uint2 w;
        w.x = pack2(o.x, o.y);
        w.y = pack2(o.z, o.w);
        aggb[(size_t)wid * 32 + q] = w;
        ssum.x += o.x; ssum.y += o.y; ssum.z += o.z; ssum.w += o.w;
        ssq.x += o.x * o.x; ssq.y += o.y * o.y;
        ssq.z += o.z * o.z; ssq.w += o.w * o.w;
    }
    redS[tid] = ssum;
    redQ[tid] = ssq;
    __syncthreads();
    if (tid < 128) {
        redS[tid].x += redS[tid+128].x; redS[tid].y += redS[tid+128].y;
        redS[tid].z += redS[tid+128].z; redS[tid].w += redS[tid+128].w;
        redQ[tid].x += redQ[tid+128].x; redQ[tid].y += redQ[tid+128].y;
        redQ[tid].z += redQ[tid+128].z; redQ[tid].w += redQ[tid+128].w;
    }
    __syncthreads();
    if (tid < 64) {
        redS[tid].x += redS[tid+64].x; redS[tid].y += redS[tid+64].y;
        redS[tid].z += redS[tid+64].z; redS[tid].w += redS[tid+64].w;
        redQ[tid].x += redQ[tid+64].x; redQ[tid].y += redQ[tid+64].y;
        redQ[tid].z += redQ[tid+64].z; redQ[tid].w += redQ[tid+64].w;
    }
    __syncthreads();
    if (tid < 32) {
        float4 s = redS[tid], s2 = redS[tid + 32];
        float4 qq = redQ[tid], q2 = redQ[tid + 32];
        s.x += s2.x; s.y += s2.y; s.z += s2.z; s.w += s2.w;
        qq.x += q2.x; qq.y += q2.y; qq.z += q2.z; qq.w += q2.w;
        partial[(size_t)blockIdx.x * 64 + tid] = s;
        partial[(size_t)blockIdx.x * 64 + 32 + tid] = qq;
    }
}

// ---------------------------------------------------------------------------
// Stage A: 64 blocks, block r reduces partial rows [r*32, (r+1)*32) -> partial2[r].
// ---------------------------------------------------------------------------
__global__ __launch_bounds__(256) void reduce_partial_kernel(const float4* __restrict__ partial,
                                                             float4* __restrict__ partial2) {
    __shared__ float4 red[256];
    int t = threadIdx.x;
    int e = t & 63;
    int sr = t >> 6;                      // 0..3
    int r0 = blockIdx.x * 32;
    float4 acc = {0.f, 0.f, 0.f, 0.f};
    for (int r = sr; r < 32; r += 4) {
        float4 v = partial[(size_t)(r0 + r) * 64 + e];
        acc.x += v.x; acc.y += v.y; acc.z += v.z; acc.w += v.w;
    }
    red[t] = acc;
    __syncthreads();
    if (sr < 2) {
        float4 o = red[t + 128];
        red[t].x += o.x; red[t].y += o.y; red[t].z += o.z; red[t].w += o.w;
    }
    __syncthreads();
    if (sr == 0) {
        float4 o = red[t + 64];
        float4 s = red[t];
        s.x += o.x; s.y += o.y; s.z += o.z; s.w += o.w;
        partial2[(size_t)blockIdx.x * 64 + e] = s;
    }
}

// ---------------------------------------------------------------------------
// Stage B: reduce 64 partial2 rows -> scale/shift per column (float4 groups).
// scsh[0..31]=scale, [32..63]=shift.
// ---------------------------------------------------------------------------
__global__ __launch_bounds__(1024) void bn_finalize_kernel(const float4* __restrict__ partial2,
                                                           const float* __restrict__ g,
                                                           const float* __restrict__ be,
                                                           float4* __restrict__ scsh,
                                                           float invn) {
    __shared__ float4 red[1024];
    int t = threadIdx.x;
    int e = t & 63;
    int rg = t >> 6;
    float4 acc = {0.f, 0.f, 0.f, 0.f};
    for (int r = rg; r < NRB; r += 16) {
        float4 v = partial2[(size_t)r * 64 + e];
        acc.x += v.x; acc.y += v.y; acc.z += v.z; acc.w += v.w;
    }
    red[t] = acc;
    __syncthreads();
#pragma unroll
    for (int s = 8; s >= 1; s >>= 1) {
        if (rg < s) {
            float4 o = red[t + s * 64];
            red[t].x += o.x; red[t].y += o.y; red[t].z += o.z; red[t].w += o.w;
        }
        __syncthreads();
    }
    if (t < 32) {
        float4 s = red[t];
        float4 qq = red[32 + t];
        float4 gg = ((const float4*)g)[t];
        float4 bbe = ((const float4*)be)[t];
        float4 mu, var, sc, sh;
        mu.x = s.x * invn; mu.y = s.y * invn; mu.z = s.z * invn; mu.w = s.w * invn;
        var.x = qq.x * invn - mu.x * mu.x; var.y = qq.y * invn - mu.y * mu.y;
        var.z = qq.z * invn - mu.z * mu.z; var.w = qq.w * invn - mu.w * mu.w;
        sc.x = gg.x * rsqrtf(var.x + BN_EPS); sc.y = gg.y * rsqrtf(var.y + BN_EPS);
        sc.z = gg.z * rsqrtf(var.z + BN_EPS); sc.w = gg.w * rsqrtf(var.w + BN_EPS);
        sh.x = bbe.x - mu.x * sc.x; sh.y = bbe.y - mu.y * sc.y;
        sh.z = bbe.z - mu.z * sc.z; sh.w = bbe.w - mu.w * sc.w;
        scsh[t] = sc;
        scsh[32 + t] = sh;
    }
}

// ---------------------------------------------------------------------------
// Final BN + PReLU: bf16 agg -> f32 output.
// ---------------------------------------------------------------------------
__global__ __launch_bounds__(256) void bn_apply_kernel(const uint2* __restrict__ aggb,
                                                       const float4* __restrict__ scsh,
                                                       const float* __restrict__ aP,
                                                       float4* __restrict__ out, int n) {
    int t = blockIdx.x * 256 + threadIdx.x;
    if (t >= n * 32) return;
    int c4 = t & 31;
    float alpha = aP[0];
    uint2 u = aggb[t];
    float4 v;
    v.x = bf_lo(u.x); v.y = bf_hi(u.x); v.z = bf_lo(u.y); v.w = bf_hi(u.y);
    float4 sc = scsh[c4];
    float4 sh = scsh[32 + c4];
    float4 y;
    y.x = v.x * sc.x + sh.x; y.y = v.y * sc.y + sh.y;
    y.z = v.z * sc.z + sh.z; y.w = v.w * sc.w + sh.w;
    y.x = y.x >= 0.f ? y.x : alpha * y.x;
    y.y = y.y >= 0.f ? y.y : alpha * y.y;
    y.z = y.z >= 0.f ? y.z : alpha * y.z;
    y.w = y.w >= 0.f ? y.w : alpha * y.w;
    out[t] = y;
}

// ---------------------------------------------------------------------------

extern "C" void kernel_launch(void* const* d_in, const int* in_sizes, int n_in,
                              void* d_out, int out_size, void* d_ws, size_t ws_size,
                              hipStream_t stream) {
    const float* x  = (const float*)d_in[0];
    const void*  ei = d_in[1];
    const float* W1 = (const float*)d_in[2];
    const float* b1 = (const float*)d_in[3];
    const float* g1 = (const float*)d_in[4];
    const float* be1= (const float*)d_in[5];
    const float* a1 = (const float*)d_in[6];
    const float* W2 = (const float*)d_in[7];
    const float* b2 = (const float*)d_in[8];
    const float* g2 = (const float*)d_in[9];
    const float* be2= (const float*)d_in[10];
    const float* a2 = (const float*)d_in[11];

    int N = in_sizes[0] / FD;
    int E = in_sizes[1] / 2;
    float* out = (float*)d_out;

    int nbuck = (N + (1 << BSH) - 1) >> BSH;   // 196 for N=50000 (<=256 required)

    char* ws = (char*)d_ws;
    size_t off = 0;
    auto alloc = [&](size_t bytes) {
        void* p = ws + off;
        off += (bytes + 255) & ~(size_t)255;
        return p;
    };
    float* dinv    = (float*)alloc((size_t)N * 4);
    int*   gcur    = (int*)alloc(256 * 4);
    uint4* nodemeta= (uint4*)alloc((size_t)N * 16);
    unsigned* slab = (unsigned*)alloc((size_t)nbuck * CAP * 4);
    int*   colslab = (int*)alloc((size_t)nbuck * CAP * 4);
    unsigned short* wf1 = (unsigned short*)alloc((size_t)FD * FD * 2);
    unsigned short* wf2 = (unsigned short*)alloc((size_t)FD * FD * 2);
    unsigned short* hs  = (unsigned short*)alloc((size_t)N * FD * 2);
    uint2* aggb    = (uint2*)alloc((size_t)N * FD * 2);
    float4* partial= (float4*)alloc((size_t)NGB * 64 * 16);
    float4* partial2=(float4*)alloc((size_t)NRB * 64 * 16);
    float4* scsh   = (float4*)alloc(64 * 16);
    (void)ws_size; (void)n_in; (void)out_size;

    // wprep also zeroes gcur (must precede partition)
    wprep_kernel<<<128, 256, 0, stream>>>(W1, W2, wf1, wf2, gcur);

    // CSR build (once; reused by both layers)
    partition_kernel<<<(E + BE - 1) / BE, 256, 0, stream>>>(ei, gcur, slab, E);
    bucket_csr_kernel<<<nbuck, 256, 0, stream>>>(slab, gcur, colslab, nodemeta, dinv, N);

    int gemm_blocks = (N + 63) / 64;
    int nt = N * 32;
    float invn = 1.0f / (float)N;

    // ---- layer 1 ----
    gemm_mfma_kernel<0><<<gemm_blocks, 256, 0, stream>>>(x, wf1, dinv, nullptr, nullptr,
                                                         hs, N);
    gather_stats_kernel<<<NGB, 256, 0, stream>>>((const uint2*)hs, nodemeta, colslab,
                                                 b1, aggb, partial, N);
    reduce_partial_kernel<<<NRB, 256, 0, stream>>>(partial, partial2);
    bn_finalize_kernel<<<1, 1024, 0, stream>>>(partial2, g1, be1, scsh, invn);

    // ---- layer 2 (BN1+PReLU1 fused into A-load, bf16 A) ----
    gemm_mfma_kernel<1><<<gemm_blocks, 256, 0, stream>>>(aggb, wf2, dinv,
                                                         scsh, a1, hs, N);
    gather_stats_kernel<<<NGB, 256, 0, stream>>>((const uint2*)hs, nodemeta, colslab,
                                                 b2, aggb, partial, N);
    reduce_partial_kernel<<<NRB, 256, 0, stream>>>(partial, partial2);
    bn_finalize_kernel<<<1, 1024, 0, stream>>>(partial2, g2, be2, scsh, invn);
    bn_apply_kernel<<<(nt + 255) / 256, 256, 0, stream>>>((const uint2*)aggb, scsh, a2,
                                                          (float4*)out, N);
}